// Round 8
// baseline (397.583 us; speedup 1.0000x reference)
//
#include <hip/hip_runtime.h>
#include <hip/hip_bf16.h>

#define SEQ_L 2048
#define NBATCH 4
#define EDIM 1024
#define NHEAD 16
#define DHEAD 64

typedef __attribute__((ext_vector_type(4))) float f32x4;
typedef __attribute__((ext_vector_type(16))) float f32x16;
typedef __attribute__((ext_vector_type(8))) short short8;
typedef unsigned short u16;
typedef unsigned long long u64;

// fold DH^-0.5 and log2(e) into Q so attention works in exp2 domain
#define QSCALE (0.125f * 1.44269504088896340736f)

__device__ __forceinline__ u16 f2bf(float f){
  unsigned u = __float_as_uint(f);
  u += 0x7fffu + ((u >> 16) & 1u);   // round-to-nearest-even
  return (u16)(u >> 16);
}
// hardware packed f32->bf16 (RNE): low16 = a, high16 = b  [T12 primitive]
__device__ __forceinline__ unsigned cvt_pk_bf16(float a, float b){
  unsigned r;
  asm("v_cvt_pk_bf16_f32 %0, %1, %2" : "=v"(r) : "v"(a), "v"(b));
  return r;
}
__device__ __forceinline__ float fexp2(float x){
  float r; asm("v_exp_f32 %0, %1" : "=v"(r) : "v"(x)); return r;
}

// ---------------- fp32 -> bf16 convert ----------------
__global__ __launch_bounds__(256) void cvt_f32_bf16(const float* __restrict__ src,
                                                    u16* __restrict__ dst, int n4){
  int i = blockIdx.x * 256 + threadIdx.x;
  if (i < n4){
    float4 v = reinterpret_cast<const float4*>(src)[i];
    uint2 o;
    o.x = cvt_pk_bf16(v.x, v.y);
    o.y = cvt_pk_bf16(v.z, v.w);
    *reinterpret_cast<uint2*>(dst + (size_t)i*4) = o;
  }
}

// ---------------- QKV projection GEMM (round-6 staging: padded LDS) --------
// f = which*1024 + h*64 + d.  bn<16 -> Q/K (Q pre-scaled by QSCALE).
// bn>=16 -> V via LDS transpose to Vt [N][H][DH][L] (coalesced 64B runs).
__global__ __launch_bounds__(256) void qkv_gemm(const u16* __restrict__ X,
                                                const u16* __restrict__ W,
                                                u16* __restrict__ Qd,
                                                u16* __restrict__ Kd,
                                                u16* __restrict__ Vt){
  __shared__ u16 SMEM[2*128*72];           // XL | WL, reused as T[128][134] for V
  u16* XL = SMEM;
  u16* WL = SMEM + 128*72;
  const int tid = threadIdx.x;
  const int lane = tid & 63;
  const int wid = tid >> 6;
  const int wr = wid >> 1, wc = wid & 1;
  const int lr = lane & 15, lg = lane >> 4;
  const int bm = blockIdx.x, bn = blockIdx.y;
  f32x4 acc[4][4] = {};
  for (int kt = 0; kt < 16; ++kt){
    __syncthreads();
#pragma unroll
    for (int it = 0; it < 4; ++it){
      int c = tid + 256*it;
      int row = c >> 3, c8 = (c & 7) * 8;
      *(short8*)&XL[row*72 + c8] = *(const short8*)&X[(bm*128 + row)*EDIM + kt*64 + c8];
      *(short8*)&WL[row*72 + c8] = *(const short8*)&W[(bn*128 + row)*EDIM + kt*64 + c8];
    }
    __syncthreads();
#pragma unroll
    for (int ks = 0; ks < 2; ++ks){
      short8 a[4], b[4];
#pragma unroll
      for (int m = 0; m < 4; ++m)  a[m]  = *(short8*)&XL[(wr*64 + m*16  + lr)*72 + ks*32 + lg*8];
#pragma unroll
      for (int nn = 0; nn < 4; ++nn) b[nn] = *(short8*)&WL[(wc*64 + nn*16 + lr)*72 + ks*32 + lg*8];
#pragma unroll
      for (int m = 0; m < 4; ++m)
#pragma unroll
        for (int nn = 0; nn < 4; ++nn)
          acc[m][nn] = __builtin_amdgcn_mfma_f32_16x16x32_bf16(a[m], b[nn], acc[m][nn], 0, 0, 0);
    }
  }
  if (bn < 16){
#pragma unroll
    for (int m = 0; m < 4; ++m){
      const int i0 = bm*128 + wr*64 + m*16 + lg*4;
      const int l = i0 >> 2;                 // i0 % 4 == 0: r indexes the batch
#pragma unroll
      for (int nn = 0; nn < 4; ++nn){
        const int f = bn*128 + wc*64 + nn*16 + lr;
        const int which = f >> 10;           // 0=Q, 1=K
        const int h = (f >> 6) & 15;
        const int d = f & 63;
        u16* dst = (which == 0) ? Qd : Kd;
        const float sc = (which == 0) ? QSCALE : 1.0f;
#pragma unroll
        for (int r = 0; r < 4; ++r)
          dst[((r*NHEAD + h)*SEQ_L + l)*DHEAD + d] = f2bf(acc[m][nn][r] * sc);
      }
    }
  } else {
    __syncthreads();                         // all waves done reading XL/WL
    u16* T = SMEM;
#pragma unroll
    for (int m = 0; m < 4; ++m){
      const int il0 = wr*64 + m*16 + lg*4;
#pragma unroll
      for (int nn = 0; nn < 4; ++nn){
        const int fl = wc*64 + nn*16 + lr;
        *(unsigned*)&T[fl*134 + il0]     = cvt_pk_bf16(acc[m][nn][0], acc[m][nn][1]);
        *(unsigned*)&T[fl*134 + il0 + 2] = cvt_pk_bf16(acc[m][nn][2], acc[m][nn][3]);
      }
    }
    __syncthreads();
    const int fl = tid & 127, nsel = tid >> 7;
    const int fV = bn*128 + fl - 2048;       // 0..1023
    const int hh = fV >> 6, dd = fV & 63;
#pragma unroll
    for (int nn2 = 0; nn2 < 2; ++nn2){
      const int n = nsel*2 + nn2;
      u16 val[32];
#pragma unroll
      for (int ll = 0; ll < 32; ++ll)
        val[ll] = T[fl*134 + ll*4 + n];
      const size_t base = ((size_t)(n*NHEAD + hh)*DHEAD + dd)*SEQ_L + (size_t)bm*32;
#pragma unroll
      for (int j = 0; j < 4; ++j)
        *(short8*)&Vt[base + j*8] = *(short8*)&val[j*8];
    }
  }
}

// ---------------- flash attention per (n,h) ----------------
// 32x32x16 MFMA core.  Block = 4 waves x 32 q-rows = 128 q; KVBLK = 64.
// Swapped QK^T: D = Kstaged x Q -> lane holds q = lane&31, 16 key-rows/reg.
// K rows staged with pi = swap(bit2,bit3) so PV A-frag for k-step s is
// exactly D regs [8s..8s+7].  P stays in registers (cvt_pk pairs).
// ROUND 8: double-buffered LDS -> ONE barrier per tile (write buf[t&1];
// barrier; compute.  Readers of buf[t&1] from t-2 are fenced by the t-1
// barrier).  Prefetch issued between write and barrier (full compute phase
// of runway).  T5 setprio around MFMA clusters.
__global__ __launch_bounds__(256) void attn(const u16* __restrict__ Qd,
                                            const u16* __restrict__ Kd,
                                            const u16* __restrict__ Vt,
                                            u16* __restrict__ Ctx){
  __shared__ u16 KL[2][64*66];   // [64 keys, pi-permuted rows][64 d]
  __shared__ u16 VtL[2][64*66];  // [64 d][64 keys]
  const int tid = threadIdx.x;
  const int lane = tid & 63;
  const int wid = tid >> 6;
  const int l31 = lane & 31, hf = lane >> 5;
  const int head = blockIdx.y;            // n*16 + h
  const int n = head >> 4, h = head & 15;
  const u16* qh  = Qd + head * (SEQ_L * DHEAD);
  const u16* kh  = Kd + head * (SEQ_L * DHEAD);
  const u16* vth = Vt + (size_t)head * (DHEAD * SEQ_L);
  const int q0 = blockIdx.x * 128 + wid * 32;
  short8 bq[4];
#pragma unroll
  for (int st = 0; st < 4; ++st)
    bq[st] = *(const short8*)&qh[(q0 + l31)*DHEAD + st*16 + hf*8];
  f32x16 acc[2] = {};                     // ctx: d = db*32 + l31, q per reg
  float mrun = -1e30f, lrun = 0.0f;       // per-lane state for q = l31
  const int srow = tid >> 3, sc8 = (tid & 7) * 8;
  const int prow = (srow & ~12) | ((srow & 4) << 1) | ((srow & 8) >> 1);  // swap b2,b3
  short8 kreg[2], vreg[2];
#pragma unroll
  for (int j = 0; j < 2; ++j){            // prologue: tile 0
    kreg[j] = *(const short8*)&kh[(j*32 + srow)*DHEAD + sc8];
    vreg[j] = *(const short8*)&vth[(size_t)(j*32 + srow)*SEQ_L + sc8];
  }

  auto step = [&](int t, u16* KLb, u16* VtLb){
    // write tile t (regs -> LDS); compiler waits the staging loads' vmcnt
    *(short8*)&KLb[prow*66 + sc8]       = kreg[0];
    *(short8*)&KLb[(prow+32)*66 + sc8]  = kreg[1];
    *(short8*)&VtLb[srow*66 + sc8]      = vreg[0];
    *(short8*)&VtLb[(srow+32)*66 + sc8] = vreg[1];
    // issue next tile's loads now: runway = barrier + full compute phase
    if (t < SEQ_L/64 - 1){
      const int kn = (t + 1) * 64;
#pragma unroll
      for (int j = 0; j < 2; ++j){
        kreg[j] = *(const short8*)&kh[(kn + j*32 + srow)*DHEAD + sc8];
        vreg[j] = *(const short8*)&vth[(size_t)(j*32 + srow)*SEQ_L + kn + sc8];
      }
    }
    __syncthreads();                      // single sync point per tile
#pragma unroll
    for (int c = 0; c < 2; ++c){          // two 32-key sub-blocks
      f32x16 sD = {0.f,0.f,0.f,0.f,0.f,0.f,0.f,0.f,0.f,0.f,0.f,0.f,0.f,0.f,0.f,0.f};
      __builtin_amdgcn_s_setprio(1);
#pragma unroll
      for (int st = 0; st < 4; ++st){
        short8 ak = *(short8*)&KLb[(c*32 + l31)*66 + st*16 + hf*8];
        sD = __builtin_amdgcn_mfma_f32_32x32x16_bf16(ak, bq[st], sD, 0, 0, 0);
      }
      __builtin_amdgcn_s_setprio(0);
      float tmax = sD[0];
#pragma unroll
      for (int r = 1; r < 16; ++r) tmax = fmaxf(tmax, sD[r]);
      tmax = fmaxf(tmax, __shfl_xor(tmax, 32));
      if (!__all(tmax <= mrun + 8.0f)){   // T13 defer-max (rare, wave-uniform)
        const float mnew = fmaxf(mrun, tmax);
        const float alpha = fexp2(mrun - mnew);
        lrun *= alpha;
        mrun = mnew;
#pragma unroll
        for (int r = 0; r < 16; ++r){
          const float aq = __shfl(alpha, (r&3) + 8*(r>>2) + 4*hf);
          acc[0][r] *= aq;
          acc[1][r] *= aq;
        }
      }
      float p[16];
      float ps = 0.f;
#pragma unroll
      for (int r = 0; r < 16; ++r){
        p[r] = fexp2(sD[r] - mrun);
        ps += p[r];
      }
      ps += __shfl_xor(ps, 32);
      lrun += ps;
#pragma unroll
      for (int s = 0; s < 2; ++s){
        union { unsigned u[4]; short8 s8; } pa;
#pragma unroll
        for (int jj = 0; jj < 4; ++jj)
          pa.u[jj] = cvt_pk_bf16(p[s*8 + jj*2], p[s*8 + jj*2 + 1]);
        __builtin_amdgcn_s_setprio(1);
#pragma unroll
        for (int db = 0; db < 2; ++db){
          short8 bv = *(short8*)&VtLb[(db*32 + l31)*66 + c*32 + s*16 + hf*8];
          acc[db] = __builtin_amdgcn_mfma_f32_32x32x16_bf16(pa.s8, bv, acc[db], 0, 0, 0);
        }
        __builtin_amdgcn_s_setprio(0);
      }
    }
  };

  for (int t = 0; t < SEQ_L/64; t += 2){
    step(t,     KL[0], VtL[0]);
    step(t + 1, KL[1], VtL[1]);
  }
  // epilogue: acc row r holds q-local = (r&3)+8*(r>>2)+4*hf; denom at lane q
#pragma unroll
  for (int r = 0; r < 16; ++r){
    const int ql = (r&3) + 8*(r>>2) + 4*hf;
    const float denom = __shfl(lrun, ql);
    const float inv = 1.0f / denom;
    const int q = q0 + ql;
#pragma unroll
    for (int db = 0; db < 2; ++db)
      Ctx[(q*NBATCH + n)*EDIM + h*DHEAD + db*32 + l31] = f2bf(acc[db][r] * inv);
  }
}

// ---------------- output projection GEMM (round-6 staging) ----------------
__global__ __launch_bounds__(256) void out_gemm(const u16* __restrict__ X,
                                                const u16* __restrict__ W,
                                                float* __restrict__ O){
  __shared__ u16 XL[128*72];
  __shared__ u16 WL[128*72];
  const int tid = threadIdx.x;
  const int lane = tid & 63;
  const int wid = tid >> 6;
  const int wr = wid >> 1, wc = wid & 1;
  const int lr = lane & 15, lg = lane >> 4;
  const int bm = blockIdx.x, bn = blockIdx.y;
  f32x4 acc[4][4] = {};
  for (int kt = 0; kt < 16; ++kt){
    __syncthreads();
#pragma unroll
    for (int it = 0; it < 4; ++it){
      int c = tid + 256*it;
      int row = c >> 3, c8 = (c & 7) * 8;
      *(short8*)&XL[row*72 + c8] = *(const short8*)&X[(bm*128 + row)*EDIM + kt*64 + c8];
      *(short8*)&WL[row*72 + c8] = *(const short8*)&W[(bn*128 + row)*EDIM + kt*64 + c8];
    }
    __syncthreads();
#pragma unroll
    for (int ks = 0; ks < 2; ++ks){
      short8 a[4], b[4];
#pragma unroll
      for (int m = 0; m < 4; ++m)  a[m]  = *(short8*)&XL[(wr*64 + m*16  + lr)*72 + ks*32 + lg*8];
#pragma unroll
      for (int nn = 0; nn < 4; ++nn) b[nn] = *(short8*)&WL[(wc*64 + nn*16 + lr)*72 + ks*32 + lg*8];
#pragma unroll
      for (int m = 0; m < 4; ++m)
#pragma unroll
        for (int nn = 0; nn < 4; ++nn)
          acc[m][nn] = __builtin_amdgcn_mfma_f32_16x16x32_bf16(a[m], b[nn], acc[m][nn], 0, 0, 0);
    }
  }
#pragma unroll
  for (int m = 0; m < 4; ++m){
    const int i0 = bm*128 + wr*64 + m*16 + lg*4;
#pragma unroll
    for (int nn = 0; nn < 4; ++nn){
      const int f = bn*128 + wc*64 + nn*16 + lr;
#pragma unroll
      for (int r = 0; r < 4; ++r)
        O[(size_t)(i0 + r)*EDIM + f] = acc[m][nn][r];
    }
  }
}

extern "C" void kernel_launch(void* const* d_in, const int* in_sizes, int n_in,
                              void* d_out, int out_size, void* d_ws, size_t ws_size,
                              hipStream_t stream){
  const float* x    = (const float*)d_in[0];
  const float* wqkv = (const float*)d_in[1];
  const float* wout = (const float*)d_in[2];
  float* out = (float*)d_out;
  u16* ws = (u16*)d_ws;
  const size_t XN  = (size_t)SEQ_L * NBATCH * EDIM; // 8388608
  const size_t WQN = (size_t)3 * EDIM * EDIM;       // 3145728
  const size_t WON = (size_t)EDIM * EDIM;           // 1048576
  u16* xb    = ws;               // bf16 x  [8192][1024]
  u16* wqkvb = xb + XN;          // bf16 Wqkv [3072][1024]
  u16* woutb = wqkvb + WQN;      // bf16 Wout [1024][1024]
  u16* qd    = woutb + WON;      // [N][H][L][DH]  (scaled by QSCALE)
  u16* kd    = qd + XN;          // [N][H][L][DH]
  u16* vt    = kd + XN;          // [N][H][DH][L]  (transposed V)
  u16* ctx   = xb;               // reuse xb after qkv_gemm consumed it

  cvt_f32_bf16<<<(int)(XN  / 1024), 256, 0, stream>>>(x,    xb,    (int)(XN  / 4));
  cvt_f32_bf16<<<(int)(WQN / 1024), 256, 0, stream>>>(wqkv, wqkvb, (int)(WQN / 4));
  cvt_f32_bf16<<<(int)(WON / 1024), 256, 0, stream>>>(wout, woutb, (int)(WON / 4));
  qkv_gemm<<<dim3(64, 24), 256, 0, stream>>>(xb, wqkvb, qd, kd, vt);
  attn    <<<dim3(16, 64), 256, 0, stream>>>(qd, kd, vt, ctx);
  out_gemm<<<dim3(64, 8),  256, 0, stream>>>(ctx, woutb, out);
}

// Round 9
// 235.280 us; speedup vs baseline: 1.6898x; 1.6898x over previous
//
#include <hip/hip_runtime.h>
#include <hip/hip_bf16.h>

#define SEQ_L 2048
#define NBATCH 4
#define EDIM 1024
#define NHEAD 16
#define DHEAD 64

typedef __attribute__((ext_vector_type(4))) float f32x4;
typedef __attribute__((ext_vector_type(16))) float f32x16;
typedef __attribute__((ext_vector_type(8))) short short8;
typedef unsigned short u16;
typedef unsigned long long u64;

// fold DH^-0.5 and log2(e) into Q so attention works in exp2 domain
#define QSCALE (0.125f * 1.44269504088896340736f)

__device__ __forceinline__ u16 f2bf(float f){
  unsigned u = __float_as_uint(f);
  u += 0x7fffu + ((u >> 16) & 1u);   // round-to-nearest-even
  return (u16)(u >> 16);
}
// hardware packed f32->bf16 (RNE): low16 = a, high16 = b  [T12 primitive]
__device__ __forceinline__ unsigned cvt_pk_bf16(float a, float b){
  unsigned r;
  asm("v_cvt_pk_bf16_f32 %0, %1, %2" : "=v"(r) : "v"(a), "v"(b));
  return r;
}
__device__ __forceinline__ float fexp2(float x){
  float r; asm("v_exp_f32 %0, %1" : "=v"(r) : "v"(x)); return r;
}

// ---------------- fp32 -> bf16 convert ----------------
__global__ __launch_bounds__(256) void cvt_f32_bf16(const float* __restrict__ src,
                                                    u16* __restrict__ dst, int n4){
  int i = blockIdx.x * 256 + threadIdx.x;
  if (i < n4){
    float4 v = reinterpret_cast<const float4*>(src)[i];
    uint2 o;
    o.x = cvt_pk_bf16(v.x, v.y);
    o.y = cvt_pk_bf16(v.z, v.w);
    *reinterpret_cast<uint2*>(dst + (size_t)i*4) = o;
  }
}

// ---------------- QKV projection GEMM (padded reg-staged LDS) --------------
// f = which*1024 + h*64 + d.  bn<16 -> Q/K (Q pre-scaled by QSCALE).
// bn>=16 -> V via LDS transpose to Vt [N][H][DH][L] (coalesced 64B runs).
__global__ __launch_bounds__(256) void qkv_gemm(const u16* __restrict__ X,
                                                const u16* __restrict__ W,
                                                u16* __restrict__ Qd,
                                                u16* __restrict__ Kd,
                                                u16* __restrict__ Vt){
  __shared__ u16 SMEM[2*128*72];           // XL | WL, reused as T[128][134] for V
  u16* XL = SMEM;
  u16* WL = SMEM + 128*72;
  const int tid = threadIdx.x;
  const int lane = tid & 63;
  const int wid = tid >> 6;
  const int wr = wid >> 1, wc = wid & 1;
  const int lr = lane & 15, lg = lane >> 4;
  const int bm = blockIdx.x, bn = blockIdx.y;
  f32x4 acc[4][4] = {};
  for (int kt = 0; kt < 16; ++kt){
    __syncthreads();
#pragma unroll
    for (int it = 0; it < 4; ++it){
      int c = tid + 256*it;
      int row = c >> 3, c8 = (c & 7) * 8;
      *(short8*)&XL[row*72 + c8] = *(const short8*)&X[(bm*128 + row)*EDIM + kt*64 + c8];
      *(short8*)&WL[row*72 + c8] = *(const short8*)&W[(bn*128 + row)*EDIM + kt*64 + c8];
    }
    __syncthreads();
#pragma unroll
    for (int ks = 0; ks < 2; ++ks){
      short8 a[4], b[4];
#pragma unroll
      for (int m = 0; m < 4; ++m)  a[m]  = *(short8*)&XL[(wr*64 + m*16  + lr)*72 + ks*32 + lg*8];
#pragma unroll
      for (int nn = 0; nn < 4; ++nn) b[nn] = *(short8*)&WL[(wc*64 + nn*16 + lr)*72 + ks*32 + lg*8];
#pragma unroll
      for (int m = 0; m < 4; ++m)
#pragma unroll
        for (int nn = 0; nn < 4; ++nn)
          acc[m][nn] = __builtin_amdgcn_mfma_f32_16x16x32_bf16(a[m], b[nn], acc[m][nn], 0, 0, 0);
    }
  }
  if (bn < 16){
#pragma unroll
    for (int m = 0; m < 4; ++m){
      const int i0 = bm*128 + wr*64 + m*16 + lg*4;
      const int l = i0 >> 2;                 // i0 % 4 == 0: r indexes the batch
#pragma unroll
      for (int nn = 0; nn < 4; ++nn){
        const int f = bn*128 + wc*64 + nn*16 + lr;
        const int which = f >> 10;           // 0=Q, 1=K
        const int h = (f >> 6) & 15;
        const int d = f & 63;
        u16* dst = (which == 0) ? Qd : Kd;
        const float sc = (which == 0) ? QSCALE : 1.0f;
#pragma unroll
        for (int r = 0; r < 4; ++r)
          dst[((r*NHEAD + h)*SEQ_L + l)*DHEAD + d] = f2bf(acc[m][nn][r] * sc);
      }
    }
  } else {
    __syncthreads();                         // all waves done reading XL/WL
    u16* T = SMEM;
#pragma unroll
    for (int m = 0; m < 4; ++m){
      const int il0 = wr*64 + m*16 + lg*4;
#pragma unroll
      for (int nn = 0; nn < 4; ++nn){
        const int fl = wc*64 + nn*16 + lr;
        *(unsigned*)&T[fl*134 + il0]     = cvt_pk_bf16(acc[m][nn][0], acc[m][nn][1]);
        *(unsigned*)&T[fl*134 + il0 + 2] = cvt_pk_bf16(acc[m][nn][2], acc[m][nn][3]);
      }
    }
    __syncthreads();
    const int fl = tid & 127, nsel = tid >> 7;
    const int fV = bn*128 + fl - 2048;       // 0..1023
    const int hh = fV >> 6, dd = fV & 63;
#pragma unroll
    for (int nn2 = 0; nn2 < 2; ++nn2){
      const int n = nsel*2 + nn2;
      u16 val[32];
#pragma unroll
      for (int ll = 0; ll < 32; ++ll)
        val[ll] = T[fl*134 + ll*4 + n];
      const size_t base = ((size_t)(n*NHEAD + hh)*DHEAD + dd)*SEQ_L + (size_t)bm*32;
#pragma unroll
      for (int j = 0; j < 4; ++j)
        *(short8*)&Vt[base + j*8] = *(short8*)&val[j*8];
    }
  }
}

// ---------------- flash attention per (n,h) ----------------
// 32x32x16 MFMA core.  Block = 4 waves x 32 q-rows = 128 q; KVBLK = 64.
// Swapped QK^T: D = Kstaged x Q -> lane holds q = lane&31, 16 key-rows/reg.
// K rows staged with pi = swap(bit2,bit3) so PV A-frag for k-step s is
// exactly D regs [8s..8s+7].  P stays in registers (cvt_pk pairs).
// ROUND 9: round-7 structure (single buffer, write;barrier;prefetch;compute)
// but with RAW s_barrier: top barrier has NO waitcnt (readers' ds_reads are
// drained by MFMA register deps before arrival); bottom barrier only
// lgkmcnt(0).  vmcnt (the prefetch) stays in flight across both barriers —
// the round-8 regression was __syncthreads' vmcnt(0) drain right after the
// prefetch issue.  T5 setprio around MFMA clusters; tree-reduced max/sum.
__global__ __launch_bounds__(256) void attn(const u16* __restrict__ Qd,
                                            const u16* __restrict__ Kd,
                                            const u16* __restrict__ Vt,
                                            u16* __restrict__ Ctx){
  __shared__ u16 KL[64*66];      // [64 keys, pi-permuted rows][64 d]
  __shared__ u16 VtL[64*66];     // [64 d][64 keys]
  const int tid = threadIdx.x;
  const int lane = tid & 63;
  const int wid = tid >> 6;
  const int l31 = lane & 31, hf = lane >> 5;
  const int head = blockIdx.y;            // n*16 + h
  const int n = head >> 4, h = head & 15;
  const u16* qh  = Qd + head * (SEQ_L * DHEAD);
  const u16* kh  = Kd + head * (SEQ_L * DHEAD);
  const u16* vth = Vt + (size_t)head * (DHEAD * SEQ_L);
  const int q0 = blockIdx.x * 128 + wid * 32;
  short8 bq[4];
#pragma unroll
  for (int st = 0; st < 4; ++st)
    bq[st] = *(const short8*)&qh[(q0 + l31)*DHEAD + st*16 + hf*8];
  f32x16 acc[2] = {};                     // ctx: d = db*32 + l31, q per reg
  float mrun = -1e30f, lrun = 0.0f;       // per-lane state for q = l31
  const int srow = tid >> 3, sc8 = (tid & 7) * 8;
  const int prow = (srow & ~12) | ((srow & 4) << 1) | ((srow & 8) >> 1);  // swap b2,b3
  short8 kreg[2], vreg[2];
#pragma unroll
  for (int j = 0; j < 2; ++j){            // prologue: tile 0
    kreg[j] = *(const short8*)&kh[(j*32 + srow)*DHEAD + sc8];
    vreg[j] = *(const short8*)&vth[(size_t)(j*32 + srow)*SEQ_L + sc8];
  }

  for (int t = 0; t < SEQ_L/64; ++t){
    // top barrier: WAR fence only.  Raw s_barrier, no waitcnt: every wave's
    // ds_reads of the previous tile were consumed by MFMAs (register dep
    // forces lgkm drain) before it arrives here.  Prefetch vmcnt stays live.
    asm volatile("" ::: "memory");
    __builtin_amdgcn_s_barrier();
    asm volatile("" ::: "memory");
    // write tile t (compiler inserts vmcnt waits for kreg/vreg here)
    *(short8*)&KL[prow*66 + sc8]       = kreg[0];
    *(short8*)&KL[(prow+32)*66 + sc8]  = kreg[1];
    *(short8*)&VtL[srow*66 + sc8]      = vreg[0];
    *(short8*)&VtL[(srow+32)*66 + sc8] = vreg[1];
    // bottom barrier: RAW fence — only LDS writes must be visible
    asm volatile("s_waitcnt lgkmcnt(0)" ::: "memory");
    __builtin_amdgcn_s_barrier();
    __builtin_amdgcn_sched_barrier(0);
    if (t < SEQ_L/64 - 1){                // T14: prefetch next tile into regs
      const int kn = (t + 1) * 64;
#pragma unroll
      for (int j = 0; j < 2; ++j){
        kreg[j] = *(const short8*)&kh[(kn + j*32 + srow)*DHEAD + sc8];
        vreg[j] = *(const short8*)&vth[(size_t)(j*32 + srow)*SEQ_L + kn + sc8];
      }
    }
#pragma unroll
    for (int c = 0; c < 2; ++c){          // two 32-key sub-blocks
      f32x16 sD = {0.f,0.f,0.f,0.f,0.f,0.f,0.f,0.f,0.f,0.f,0.f,0.f,0.f,0.f,0.f,0.f};
      __builtin_amdgcn_s_setprio(1);
#pragma unroll
      for (int st = 0; st < 4; ++st){
        short8 ak = *(short8*)&KL[(c*32 + l31)*66 + st*16 + hf*8];
        sD = __builtin_amdgcn_mfma_f32_32x32x16_bf16(ak, bq[st], sD, 0, 0, 0);
      }
      __builtin_amdgcn_s_setprio(0);
      // tile max: balanced tree (depth 4) + cross-half
      float mx[8];
#pragma unroll
      for (int r = 0; r < 8; ++r) mx[r] = fmaxf(sD[r], sD[r+8]);
#pragma unroll
      for (int r = 0; r < 4; ++r) mx[r] = fmaxf(mx[r], mx[r+4]);
      float tmax = fmaxf(fmaxf(mx[0], mx[1]), fmaxf(mx[2], mx[3]));
      tmax = fmaxf(tmax, __shfl_xor(tmax, 32));
      if (!__all(tmax <= mrun + 8.0f)){   // T13 defer-max (rare, wave-uniform)
        const float mnew = fmaxf(mrun, tmax);
        const float alpha = fexp2(mrun - mnew);
        lrun *= alpha;
        mrun = mnew;
#pragma unroll
        for (int r = 0; r < 16; ++r){
          const float aq = __shfl(alpha, (r&3) + 8*(r>>2) + 4*hf);
          acc[0][r] *= aq;
          acc[1][r] *= aq;
        }
      }
      float p[16];
#pragma unroll
      for (int r = 0; r < 16; ++r)
        p[r] = fexp2(sD[r] - mrun);
      // tree sum
      float s8v[8];
#pragma unroll
      for (int r = 0; r < 8; ++r) s8v[r] = p[r] + p[r+8];
#pragma unroll
      for (int r = 0; r < 4; ++r) s8v[r] = s8v[r] + s8v[r+4];
      float ps = (s8v[0] + s8v[1]) + (s8v[2] + s8v[3]);
      ps += __shfl_xor(ps, 32);
      lrun += ps;
#pragma unroll
      for (int s = 0; s < 2; ++s){
        union { unsigned u[4]; short8 s8; } pa;
#pragma unroll
        for (int jj = 0; jj < 4; ++jj)
          pa.u[jj] = cvt_pk_bf16(p[s*8 + jj*2], p[s*8 + jj*2 + 1]);
        __builtin_amdgcn_s_setprio(1);
#pragma unroll
        for (int db = 0; db < 2; ++db){
          short8 bv = *(short8*)&VtL[(db*32 + l31)*66 + c*32 + s*16 + hf*8];
          acc[db] = __builtin_amdgcn_mfma_f32_32x32x16_bf16(pa.s8, bv, acc[db], 0, 0, 0);
        }
        __builtin_amdgcn_s_setprio(0);
      }
    }
  }
  // epilogue: acc row r holds q-local = (r&3)+8*(r>>2)+4*hf; denom at lane q
#pragma unroll
  for (int r = 0; r < 16; ++r){
    const int ql = (r&3) + 8*(r>>2) + 4*hf;
    const float denom = __shfl(lrun, ql);
    const float inv = 1.0f / denom;
    const int q = q0 + ql;
#pragma unroll
    for (int db = 0; db < 2; ++db)
      Ctx[(q*NBATCH + n)*EDIM + h*DHEAD + db*32 + l31] = f2bf(acc[db][r] * inv);
  }
}

// ---------------- output projection GEMM (padded reg-staged LDS) -----------
__global__ __launch_bounds__(256) void out_gemm(const u16* __restrict__ X,
                                                const u16* __restrict__ W,
                                                float* __restrict__ O){
  __shared__ u16 XL[128*72];
  __shared__ u16 WL[128*72];
  const int tid = threadIdx.x;
  const int lane = tid & 63;
  const int wid = tid >> 6;
  const int wr = wid >> 1, wc = wid & 1;
  const int lr = lane & 15, lg = lane >> 4;
  const int bm = blockIdx.x, bn = blockIdx.y;
  f32x4 acc[4][4] = {};
  for (int kt = 0; kt < 16; ++kt){
    __syncthreads();
#pragma unroll
    for (int it = 0; it < 4; ++it){
      int c = tid + 256*it;
      int row = c >> 3, c8 = (c & 7) * 8;
      *(short8*)&XL[row*72 + c8] = *(const short8*)&X[(bm*128 + row)*EDIM + kt*64 + c8];
      *(short8*)&WL[row*72 + c8] = *(const short8*)&W[(bn*128 + row)*EDIM + kt*64 + c8];
    }
    __syncthreads();
#pragma unroll
    for (int ks = 0; ks < 2; ++ks){
      short8 a[4], b[4];
#pragma unroll
      for (int m = 0; m < 4; ++m)  a[m]  = *(short8*)&XL[(wr*64 + m*16  + lr)*72 + ks*32 + lg*8];
#pragma unroll
      for (int nn = 0; nn < 4; ++nn) b[nn] = *(short8*)&WL[(wc*64 + nn*16 + lr)*72 + ks*32 + lg*8];
#pragma unroll
      for (int m = 0; m < 4; ++m)
#pragma unroll
        for (int nn = 0; nn < 4; ++nn)
          acc[m][nn] = __builtin_amdgcn_mfma_f32_16x16x32_bf16(a[m], b[nn], acc[m][nn], 0, 0, 0);
    }
  }
#pragma unroll
  for (int m = 0; m < 4; ++m){
    const int i0 = bm*128 + wr*64 + m*16 + lg*4;
#pragma unroll
    for (int nn = 0; nn < 4; ++nn){
      const int f = bn*128 + wc*64 + nn*16 + lr;
#pragma unroll
      for (int r = 0; r < 4; ++r)
        O[(size_t)(i0 + r)*EDIM + f] = acc[m][nn][r];
    }
  }
}

extern "C" void kernel_launch(void* const* d_in, const int* in_sizes, int n_in,
                              void* d_out, int out_size, void* d_ws, size_t ws_size,
                              hipStream_t stream){
  const float* x    = (const float*)d_in[0];
  const float* wqkv = (const float*)d_in[1];
  const float* wout = (const float*)d_in[2];
  float* out = (float*)d_out;
  u16* ws = (u16*)d_ws;
  const size_t XN  = (size_t)SEQ_L * NBATCH * EDIM; // 8388608
  const size_t WQN = (size_t)3 * EDIM * EDIM;       // 3145728
  const size_t WON = (size_t)EDIM * EDIM;           // 1048576
  u16* xb    = ws;               // bf16 x  [8192][1024]
  u16* wqkvb = xb + XN;          // bf16 Wqkv [3072][1024]
  u16* woutb = wqkvb + WQN;      // bf16 Wout [1024][1024]
  u16* qd    = woutb + WON;      // [N][H][L][DH]  (scaled by QSCALE)
  u16* kd    = qd + XN;          // [N][H][L][DH]
  u16* vt    = kd + XN;          // [N][H][DH][L]  (transposed V)
  u16* ctx   = xb;               // reuse xb after qkv_gemm consumed it

  cvt_f32_bf16<<<(int)(XN  / 1024), 256, 0, stream>>>(x,    xb,    (int)(XN  / 4));
  cvt_f32_bf16<<<(int)(WQN / 1024), 256, 0, stream>>>(wqkv, wqkvb, (int)(WQN / 4));
  cvt_f32_bf16<<<(int)(WON / 1024), 256, 0, stream>>>(wout, woutb, (int)(WON / 4));
  qkv_gemm<<<dim3(64, 24), 256, 0, stream>>>(xb, wqkvb, qd, kd, vt);
  attn    <<<dim3(16, 64), 256, 0, stream>>>(qd, kd, vt, ctx);
  out_gemm<<<dim3(64, 8),  256, 0, stream>>>(ctx, woutb, out);
}